// Round 10
// baseline (140.758 us; speedup 1.0000x reference)
//
#include <hip/hip_runtime.h>
#include <hip/hip_bf16.h>

typedef __attribute__((ext_vector_type(8))) short short8;
typedef __attribute__((ext_vector_type(16))) float f32x16;

__device__ __forceinline__ unsigned short bfbits(float f) {
  return __builtin_bit_cast(unsigned short, __float2bfloat16(f));
}

__device__ __forceinline__ short8 lds_read16(const short* p, int byteOff) {
  return *reinterpret_cast<const short8*>(reinterpret_cast<const char*>(p) + byteOff);
}

#define MFMA(a, b, c) __builtin_amdgcn_mfma_f32_32x32x16_bf16((a), (b), (c), 0, 0, 0)

// x:[524288][64] f32 (flat reinterpret of [B,E,S,D]; expert = row>>16)
// w1:[8][64][256] f32, w2:[8][256][64] f32, out same shape as x.
// Grid 512 x 512 threads. expert = blockIdx&7 (XCD-pinned), chunk =
// blockIdx>>3 owns 1024 rows; 8 waves x 4 tiles x 32 rows.
//
// Measured history: R7 (256thr, unroll-2 staging) 86.7 us, FETCH 67 MB
// (x L3-resident), MfmaUtil 12%, Occ 10% (2 w/SIMD). R8 deeper prefetch:
// null -> not load-latency on the prefetch path. R9 two-tile ILP: -6%
// (VGPR 212). Conclusion: wave-starved, not ILP-starved. R10: 512-thread
// blocks -> 2 blocks/CU (LDS) x 8 waves = 4 waves/SIMD (2x TLP), with the
// LEAN body (no x prefetch) capped at 128 VGPR via launch_bounds(512,2)
// (cap semantics measured R2/R3). Live-set audit ~115-125 -> no spill
// expected; verify via FETCH staying ~70 MB.
__launch_bounds__(512, 2)
__global__ void ffn_fused(const float* __restrict__ x,
                          const float* __restrict__ w1,
                          const float* __restrict__ w2,
                          float* __restrict__ out) {
  // W1^T: [f=256][d=64] bf16, row pitch 128 B, byte ^= (f&7)<<4
  // W2^T: [d=64][f=256] bf16, row pitch 512 B, byte ^= (d&31)<<4
  __shared__ short w1t[256 * 64];
  __shared__ short w2t[64 * 256];

  const int tid  = threadIdx.x;
  const int lane = tid & 63;
  const int wv   = tid >> 6;   // wave 0..7
  const int m    = lane & 31;
  const int g    = lane >> 5;

  const int e     = blockIdx.x & 7;   // expert -> XCD pinned (128 KB weights/XCD-L2)
  const int chunk = blockIdx.x >> 3;  // 0..63

  const float* W1 = w1 + e * (64 * 256);
  const float* W2 = w2 + e * (256 * 64);

  const long rowBase = (long)e * 65536 + (long)chunk * 1024 + wv * 128;

  // ---- stage W1^T: thread handles column f = tid&255, half = tid>>8 ----
  // unroll 2: bound in-flight staging loads (full unroll spills ~64 dw/thread)
  {
    const int f    = tid & 255;
    const int half = tid >> 8;
    const int swz  = (f & 7) << 4;
#pragma unroll 2
    for (int i = 0; i < 8; ++i) {
      const int iq = half * 8 + i;
      float a0 = W1[(4 * iq + 0) * 256 + f];
      float a1 = W1[(4 * iq + 1) * 256 + f];
      float a2 = W1[(4 * iq + 2) * 256 + f];
      float a3 = W1[(4 * iq + 3) * 256 + f];
      unsigned lo = (unsigned)bfbits(a0) | ((unsigned)bfbits(a1) << 16);
      unsigned hi = (unsigned)bfbits(a2) | ((unsigned)bfbits(a3) << 16);
      const int off = (f * 128 + iq * 8) ^ swz;
      *reinterpret_cast<uint2*>(reinterpret_cast<char*>(w1t) + off) = make_uint2(lo, hi);
    }
  }
  // ---- stage W2^T: thread handles column d = tid&63, f-quad block tid>>6 ----
  {
    const int d   = tid & 63;
    const int fb  = tid >> 6;  // 0..7
    const int swz = (d & 31) << 4;
#pragma unroll 2
    for (int i = 0; i < 8; ++i) {
      const int f4 = fb + 8 * i;
      const int f  = 4 * f4;
      float a0 = W2[(f + 0) * 64 + d];
      float a1 = W2[(f + 1) * 64 + d];
      float a2 = W2[(f + 2) * 64 + d];
      float a3 = W2[(f + 3) * 64 + d];
      unsigned lo = (unsigned)bfbits(a0) | ((unsigned)bfbits(a1) << 16);
      unsigned hi = (unsigned)bfbits(a2) | ((unsigned)bfbits(a3) << 16);
      const int off = (d * 512 + f4 * 8) ^ swz;
      *reinterpret_cast<uint2*>(reinterpret_cast<char*>(w2t) + off) = make_uint2(lo, hi);
    }
  }
  __syncthreads();  // only barrier in the kernel

  const int swzm = (m & 7) << 4;
  const int swzd = m << 4;  // ((d&31)<<4, d = m and 32+m give same value)

  for (int it = 0; it < 4; ++it) {
    const long rb = rowBase + it * 32;  // this wave's 32 rows this tile

    // ---- load + convert x fragments (no prefetch buffer: TLP covers the
    //      L3 latency at 4 waves/SIMD; saves 32 VGPRs) ----
    short8 xf[4];
#pragma unroll
    for (int ks = 0; ks < 4; ++ks) {
      const float* px = x + (rb + m) * 64 + ks * 16 + g * 8;
      const float4 u0 = *reinterpret_cast<const float4*>(px);
      const float4 u1 = *reinterpret_cast<const float4*>(px + 4);
      short8 v;
      v[0] = (short)bfbits(u0.x); v[1] = (short)bfbits(u0.y);
      v[2] = (short)bfbits(u0.z); v[3] = (short)bfbits(u0.w);
      v[4] = (short)bfbits(u1.x); v[5] = (short)bfbits(u1.y);
      v[6] = (short)bfbits(u1.z); v[7] = (short)bfbits(u1.w);
      xf[ks] = v;
    }

    f32x16 o0, o1;  // out^T acc per dt half
#pragma unroll
    for (int i = 0; i < 16; ++i) { o0[i] = 0.f; o1[i] = 0.f; }

#pragma unroll
    for (int ft = 0; ft < 8; ++ft) {
      // GEMM1: h^T tile [32f x 32m] = W1^T frag x x^T frag, K=64 (4 steps)
      short8 a[4];
#pragma unroll
      for (int ks = 0; ks < 4; ++ks)
        a[ks] = lds_read16(w1t, ((ft * 32 + m) * 128 + ks * 32 + g * 16) ^ swzm);

      f32x16 h;
#pragma unroll
      for (int i = 0; i < 16; ++i) h[i] = 0.f;
#pragma unroll
      for (int ks = 0; ks < 4; ++ks) h = MFMA(a[ks], xf[ks], h);

      // relu + pack to bf16 pairs: pk[2q+hh] covers C regs 4q..4q+3
      unsigned pk[8];
#pragma unroll
      for (int q = 0; q < 4; ++q) {
        pk[2*q]   = (unsigned)bfbits(fmaxf(h[4*q+0], 0.f)) | ((unsigned)bfbits(fmaxf(h[4*q+1], 0.f)) << 16);
        pk[2*q+1] = (unsigned)bfbits(fmaxf(h[4*q+2], 0.f)) | ((unsigned)bfbits(fmaxf(h[4*q+3], 0.f)) << 16);
      }

      // GEMM2: out^T += W2^T frag x h^T frag; h^T B-frag built in-register
      // via one cross-half __shfl_xor(32) pair per fragment (PROVEN R1/R3).
#pragma unroll
      for (int sub = 0; sub < 2; ++sub) {
        const int ks2 = 2 * ft + sub;
        const short8 wA = lds_read16(w2t, (m * 512 + ks2 * 32 + g * 16) ^ swzd);
        const short8 wB = lds_read16(w2t, ((32 + m) * 512 + ks2 * 32 + g * 16) ^ swzd);
        const int qa = 2 * sub, qb = 2 * sub + 1;

        union { short8 v; unsigned u[4]; } b;
        {
          unsigned pa0 = pk[2*qa], pa1 = pk[2*qa+1];
          unsigned pb0 = pk[2*qb], pb1 = pk[2*qb+1];
          unsigned s0 = g ? pa0 : pb0, s1 = g ? pa1 : pb1;  // what partner needs
          unsigned k0 = g ? pb0 : pa0, k1 = g ? pb1 : pa1;  // what I keep
          unsigned r0 = __shfl_xor(s0, 32, 64);
          unsigned r1 = __shfl_xor(s1, 32, 64);
          b.u[0] = g ? r0 : k0; b.u[1] = g ? r1 : k1;
          b.u[2] = g ? k0 : r0; b.u[3] = g ? k1 : r1;
        }

        o0 = MFMA(wA, b.v, o0);
        o1 = MFMA(wB, b.v, o1);
      }
    }

    // ---- store out^T C-frags: 4 consecutive d per reg-quad -> float4 stores ----
#pragma unroll
    for (int dt = 0; dt < 2; ++dt) {
      const f32x16& acc = dt == 0 ? o0 : o1;
      float* po = out + (rb + m) * 64 + dt * 32 + g * 4;
#pragma unroll
      for (int q = 0; q < 4; ++q) {
        float4 s;
        s.x = acc[4*q+0]; s.y = acc[4*q+1]; s.z = acc[4*q+2]; s.w = acc[4*q+3];
        *reinterpret_cast<float4*>(po + 8 * q) = s;  // d = dt*32 + 8q + 4g + 0..3
      }
    }
  }
}

extern "C" void kernel_launch(void* const* d_in, const int* in_sizes, int n_in,
                              void* d_out, int out_size, void* d_ws, size_t ws_size,
                              hipStream_t stream) {
  const float* x  = (const float*)d_in[0];
  const float* w1 = (const float*)d_in[1];
  const float* w2 = (const float*)d_in[2];
  float* out = (float*)d_out;
  ffn_fused<<<dim3(512), dim3(512), 0, stream>>>(x, w1, w2, out);
}

// Round 11
// 67.475 us; speedup vs baseline: 2.0861x; 2.0861x over previous
//
#include <hip/hip_runtime.h>
#include <hip/hip_bf16.h>

typedef __attribute__((ext_vector_type(8))) short short8;
typedef __attribute__((ext_vector_type(16))) float f32x16;

__device__ __forceinline__ unsigned short bfbits(float f) {
  return __builtin_bit_cast(unsigned short, __float2bfloat16(f));
}

__device__ __forceinline__ short8 lds_read16(const short* p, int byteOff) {
  return *reinterpret_cast<const short8*>(reinterpret_cast<const char*>(p) + byteOff);
}

#define MFMA(a, b, c) __builtin_amdgcn_mfma_f32_32x32x16_bf16((a), (b), (c), 0, 0, 0)

// x:[524288][64] f32 (flat reinterpret of [B,E,S,D]; expert = row>>16)
// w1:[8][64][256] f32, w2:[8][256][64] f32, out same shape as x.
// Grid 512 x 512 threads. expert = blockIdx&7 (XCD-pinned), chunk =
// blockIdx>>3 owns 1024 rows; 8 waves x 4 tiles x 32 rows.
//
// Measured history: R7 (256thr, no cap) = 86.7us, VGPR 192, no spill, Occ 10%
// (2 w/SIMD). R10 (512thr, 128 cap, unrolled loops) = 140us: occupancy doubled
// to 21.6% BUT full unroll of it/ft loops let the scheduler stretch live
// ranges to ~150+ -> ~150 MB spill traffic (FETCH 218/WRITE 207).
// R11 = R10 + #pragma unroll 1 on it- and ft-loops: bound the scheduling
// window so live set stays ~110 < 128 cap (same mechanism as the R7 staging
// unroll-2 fix, applied to the main loop). 4 waves/SIMD of TLP covers
// per-iteration latency; cross-iteration ILP not needed.
__launch_bounds__(512, 2)
__global__ void ffn_fused(const float* __restrict__ x,
                          const float* __restrict__ w1,
                          const float* __restrict__ w2,
                          float* __restrict__ out) {
  // W1^T: [f=256][d=64] bf16, row pitch 128 B, byte ^= (f&7)<<4
  // W2^T: [d=64][f=256] bf16, row pitch 512 B, byte ^= (d&31)<<4
  __shared__ short w1t[256 * 64];
  __shared__ short w2t[64 * 256];

  const int tid  = threadIdx.x;
  const int lane = tid & 63;
  const int wv   = tid >> 6;   // wave 0..7
  const int m    = lane & 31;
  const int g    = lane >> 5;

  const int e     = blockIdx.x & 7;   // expert -> XCD pinned (128 KB weights/XCD-L2)
  const int chunk = blockIdx.x >> 3;  // 0..63

  const float* W1 = w1 + e * (64 * 256);
  const float* W2 = w2 + e * (256 * 64);

  const long rowBase = (long)e * 65536 + (long)chunk * 1024 + wv * 128;

  // ---- stage W1^T: thread handles column f = tid&255, half = tid>>8 ----
  // unroll 2: bound in-flight staging loads (full unroll spills ~64 dw/thread)
  {
    const int f    = tid & 255;
    const int half = tid >> 8;
    const int swz  = (f & 7) << 4;
#pragma unroll 2
    for (int i = 0; i < 8; ++i) {
      const int iq = half * 8 + i;
      float a0 = W1[(4 * iq + 0) * 256 + f];
      float a1 = W1[(4 * iq + 1) * 256 + f];
      float a2 = W1[(4 * iq + 2) * 256 + f];
      float a3 = W1[(4 * iq + 3) * 256 + f];
      unsigned lo = (unsigned)bfbits(a0) | ((unsigned)bfbits(a1) << 16);
      unsigned hi = (unsigned)bfbits(a2) | ((unsigned)bfbits(a3) << 16);
      const int off = (f * 128 + iq * 8) ^ swz;
      *reinterpret_cast<uint2*>(reinterpret_cast<char*>(w1t) + off) = make_uint2(lo, hi);
    }
  }
  // ---- stage W2^T: thread handles column d = tid&63, f-quad block tid>>6 ----
  {
    const int d   = tid & 63;
    const int fb  = tid >> 6;  // 0..7
    const int swz = (d & 31) << 4;
#pragma unroll 2
    for (int i = 0; i < 8; ++i) {
      const int f4 = fb + 8 * i;
      const int f  = 4 * f4;
      float a0 = W2[(f + 0) * 64 + d];
      float a1 = W2[(f + 1) * 64 + d];
      float a2 = W2[(f + 2) * 64 + d];
      float a3 = W2[(f + 3) * 64 + d];
      unsigned lo = (unsigned)bfbits(a0) | ((unsigned)bfbits(a1) << 16);
      unsigned hi = (unsigned)bfbits(a2) | ((unsigned)bfbits(a3) << 16);
      const int off = (d * 512 + f4 * 8) ^ swz;
      *reinterpret_cast<uint2*>(reinterpret_cast<char*>(w2t) + off) = make_uint2(lo, hi);
    }
  }
  __syncthreads();  // only barrier in the kernel

  const int swzm = (m & 7) << 4;
  const int swzd = m << 4;  // ((d&31)<<4, d = m and 32+m give same value)

#pragma unroll 1
  for (int it = 0; it < 4; ++it) {
    const long rb = rowBase + it * 32;  // this wave's 32 rows this tile

    // ---- load + convert x fragments ----
    short8 xf[4];
#pragma unroll
    for (int ks = 0; ks < 4; ++ks) {
      const float* px = x + (rb + m) * 64 + ks * 16 + g * 8;
      const float4 u0 = *reinterpret_cast<const float4*>(px);
      const float4 u1 = *reinterpret_cast<const float4*>(px + 4);
      short8 v;
      v[0] = (short)bfbits(u0.x); v[1] = (short)bfbits(u0.y);
      v[2] = (short)bfbits(u0.z); v[3] = (short)bfbits(u0.w);
      v[4] = (short)bfbits(u1.x); v[5] = (short)bfbits(u1.y);
      v[6] = (short)bfbits(u1.z); v[7] = (short)bfbits(u1.w);
      xf[ks] = v;
    }

    f32x16 o0, o1;  // out^T acc per dt half
#pragma unroll
    for (int i = 0; i < 16; ++i) { o0[i] = 0.f; o1[i] = 0.f; }

#pragma unroll 1
    for (int ft = 0; ft < 8; ++ft) {
      // GEMM1: h^T tile [32f x 32m] = W1^T frag x x^T frag, K=64 (4 steps)
      short8 a[4];
#pragma unroll
      for (int ks = 0; ks < 4; ++ks)
        a[ks] = lds_read16(w1t, ((ft * 32 + m) * 128 + ks * 32 + g * 16) ^ swzm);

      f32x16 h;
#pragma unroll
      for (int i = 0; i < 16; ++i) h[i] = 0.f;
#pragma unroll
      for (int ks = 0; ks < 4; ++ks) h = MFMA(a[ks], xf[ks], h);

      // relu + pack to bf16 pairs: pk[2q+hh] covers C regs 4q..4q+3
      unsigned pk[8];
#pragma unroll
      for (int q = 0; q < 4; ++q) {
        pk[2*q]   = (unsigned)bfbits(fmaxf(h[4*q+0], 0.f)) | ((unsigned)bfbits(fmaxf(h[4*q+1], 0.f)) << 16);
        pk[2*q+1] = (unsigned)bfbits(fmaxf(h[4*q+2], 0.f)) | ((unsigned)bfbits(fmaxf(h[4*q+3], 0.f)) << 16);
      }

      // GEMM2: out^T += W2^T frag x h^T frag; h^T B-frag built in-register
      // via one cross-half __shfl_xor(32) pair per fragment (PROVEN R1/R3).
#pragma unroll
      for (int sub = 0; sub < 2; ++sub) {
        const int ks2 = 2 * ft + sub;
        const short8 wA = lds_read16(w2t, (m * 512 + ks2 * 32 + g * 16) ^ swzd);
        const short8 wB = lds_read16(w2t, ((32 + m) * 512 + ks2 * 32 + g * 16) ^ swzd);
        const int qa = 2 * sub, qb = 2 * sub + 1;

        union { short8 v; unsigned u[4]; } b;
        {
          unsigned pa0 = pk[2*qa], pa1 = pk[2*qa+1];
          unsigned pb0 = pk[2*qb], pb1 = pk[2*qb+1];
          unsigned s0 = g ? pa0 : pb0, s1 = g ? pa1 : pb1;  // what partner needs
          unsigned k0 = g ? pb0 : pa0, k1 = g ? pb1 : pa1;  // what I keep
          unsigned r0 = __shfl_xor(s0, 32, 64);
          unsigned r1 = __shfl_xor(s1, 32, 64);
          b.u[0] = g ? r0 : k0; b.u[1] = g ? r1 : k1;
          b.u[2] = g ? k0 : r0; b.u[3] = g ? k1 : r1;
        }

        o0 = MFMA(wA, b.v, o0);
        o1 = MFMA(wB, b.v, o1);
      }
    }

    // ---- store out^T C-frags: 4 consecutive d per reg-quad -> float4 stores ----
#pragma unroll
    for (int dt = 0; dt < 2; ++dt) {
      const f32x16& acc = dt == 0 ? o0 : o1;
      float* po = out + (rb + m) * 64 + dt * 32 + g * 4;
#pragma unroll
      for (int q = 0; q < 4; ++q) {
        float4 s;
        s.x = acc[4*q+0]; s.y = acc[4*q+1]; s.z = acc[4*q+2]; s.w = acc[4*q+3];
        *reinterpret_cast<float4*>(po + 8 * q) = s;  // d = dt*32 + 8q + 4g + 0..3
      }
    }
  }
}

extern "C" void kernel_launch(void* const* d_in, const int* in_sizes, int n_in,
                              void* d_out, int out_size, void* d_ws, size_t ws_size,
                              hipStream_t stream) {
  const float* x  = (const float*)d_in[0];
  const float* w1 = (const float*)d_in[1];
  const float* w2 = (const float*)d_in[2];
  float* out = (float*)d_out;
  ffn_fused<<<dim3(512), dim3(512), 0, stream>>>(x, w1, w2, out);
}